// Round 12
// baseline (1353.580 us; speedup 1.0000x reference)
//
#include <hip/hip_runtime.h>
#include <hip/hip_bf16.h>

// ---------------------------------------------------------------------------
// HID=512 POOL=4096 N_OBJ_CLS=151 N_REL_CLS=51 EMB=200 N_OBJ=1024 N_REL=128
// ---------------------------------------------------------------------------

typedef __attribute__((ext_vector_type(8))) short  s16x8;
typedef __attribute__((ext_vector_type(4))) short  s16x4;
typedef __attribute__((ext_vector_type(4))) float  f32x4;

__device__ inline unsigned short f2bf(float f) {
    unsigned u = __builtin_bit_cast(unsigned, f);
    u = (u + 0x7FFF + ((u >> 16) & 1)) >> 16;
    return (unsigned short)u;
}
__device__ inline float bf2f(unsigned short s) {
    unsigned u = ((unsigned)s) << 16;
    return __builtin_bit_cast(float, u);
}

// bijective chunked XCD swizzle (m204): neighbor work items land on same XCD
__device__ inline int xcd_swz(int o, int n) {
    const int q = n >> 3, r = n & 7;
    const int x = o & 7, j = o >> 3;
    const int base = (x < r) ? x * (q + 1) : r * (q + 1) + (x - r) * q;
    return base + j;
}

// ======================= generic f32 GEMM (64x64 tile) ======================
template<bool BT, bool RELU, bool MUL>
__global__ __launch_bounds__(256) void gemm_kernel(
    const float* __restrict__ A, const float* __restrict__ B,
    const float* __restrict__ bias, const float* __restrict__ mulp,
    float* __restrict__ C, int M, int N, int K)
{
    __shared__ float As[16][68];
    __shared__ float Bs[16][68];
    const int m0 = blockIdx.x * 64, n0 = blockIdx.y * 64;
    const int tid = threadIdx.x;
    const int ty = tid >> 4, tx = tid & 15;
    float acc[4][4] = {};
    for (int k0 = 0; k0 < K; k0 += 16) {
        {
            const int m = tid >> 2, kq = (tid & 3) << 2;
            const float4 a = *reinterpret_cast<const float4*>(A + (size_t)(m0 + m) * K + k0 + kq);
            As[kq + 0][m] = a.x; As[kq + 1][m] = a.y; As[kq + 2][m] = a.z; As[kq + 3][m] = a.w;
        }
        if (!BT) {
            const int kk = tid >> 4, nq = (tid & 15) << 2;
            const float4 b = *reinterpret_cast<const float4*>(B + (size_t)(k0 + kk) * N + n0 + nq);
            *reinterpret_cast<float4*>(&Bs[kk][nq]) = b;
        } else {
            const int nn = tid >> 2, kq = (tid & 3) << 2;
            const float4 b = *reinterpret_cast<const float4*>(B + (size_t)(n0 + nn) * K + k0 + kq);
            Bs[kq + 0][nn] = b.x; Bs[kq + 1][nn] = b.y; Bs[kq + 2][nn] = b.z; Bs[kq + 3][nn] = b.w;
        }
        __syncthreads();
#pragma unroll
        for (int k = 0; k < 16; ++k) {
            const float4 av = *reinterpret_cast<const float4*>(&As[k][ty << 2]);
            const float4 bv = *reinterpret_cast<const float4*>(&Bs[k][tx << 2]);
            acc[0][0] += av.x * bv.x; acc[0][1] += av.x * bv.y; acc[0][2] += av.x * bv.z; acc[0][3] += av.x * bv.w;
            acc[1][0] += av.y * bv.x; acc[1][1] += av.y * bv.y; acc[1][2] += av.y * bv.z; acc[1][3] += av.y * bv.w;
            acc[2][0] += av.z * bv.x; acc[2][1] += av.z * bv.y; acc[2][2] += av.z * bv.z; acc[2][3] += av.z * bv.w;
            acc[3][0] += av.w * bv.x; acc[3][1] += av.w * bv.y; acc[3][2] += av.w * bv.z; acc[3][3] += av.w * bv.w;
        }
        __syncthreads();
    }
#pragma unroll
    for (int i = 0; i < 4; ++i) {
        const int m = m0 + (ty << 2) + i;
#pragma unroll
        for (int j = 0; j < 4; ++j) {
            const int n = n0 + (tx << 2) + j;
            float v = acc[i][j] + bias[n];
            if (MUL) v *= mulp[(size_t)m * N + n];
            if (RELU) v = fmaxf(v, 0.f);
            C[(size_t)m * N + n] = v;
        }
    }
}

// =================== split-K f32 GEMM: partials + reduce ====================
template<bool BT>
__global__ __launch_bounds__(256) void gemmsk_kernel(
    const float* __restrict__ A, const float* __restrict__ B,
    float* __restrict__ part, int M, int N, int K, int kchunk)
{
    __shared__ float As[16][68];
    __shared__ float Bs[16][68];
    const int m0 = blockIdx.x * 64, n0 = blockIdx.y * 64;
    const int kbeg = blockIdx.z * kchunk, kend = kbeg + kchunk;
    const int tid = threadIdx.x;
    const int ty = tid >> 4, tx = tid & 15;
    float acc[4][4] = {};
    for (int k0 = kbeg; k0 < kend; k0 += 16) {
        {
            const int m = tid >> 2, kq = (tid & 3) << 2;
            const float4 a = *reinterpret_cast<const float4*>(A + (size_t)(m0 + m) * K + k0 + kq);
            As[kq + 0][m] = a.x; As[kq + 1][m] = a.y; As[kq + 2][m] = a.z; As[kq + 3][m] = a.w;
        }
        if (!BT) {
            const int kk = tid >> 4, nq = (tid & 15) << 2;
            const float4 b = *reinterpret_cast<const float4*>(B + (size_t)(k0 + kk) * N + n0 + nq);
            *reinterpret_cast<float4*>(&Bs[kk][nq]) = b;
        } else {
            const int nn = tid >> 2, kq = (tid & 3) << 2;
            const float4 b = *reinterpret_cast<const float4*>(B + (size_t)(n0 + nn) * K + k0 + kq);
            Bs[kq + 0][nn] = b.x; Bs[kq + 1][nn] = b.y; Bs[kq + 2][nn] = b.z; Bs[kq + 3][nn] = b.w;
        }
        __syncthreads();
#pragma unroll
        for (int k = 0; k < 16; ++k) {
            const float4 av = *reinterpret_cast<const float4*>(&As[k][ty << 2]);
            const float4 bv = *reinterpret_cast<const float4*>(&Bs[k][tx << 2]);
            acc[0][0] += av.x * bv.x; acc[0][1] += av.x * bv.y; acc[0][2] += av.x * bv.z; acc[0][3] += av.x * bv.w;
            acc[1][0] += av.y * bv.x; acc[1][1] += av.y * bv.y; acc[1][2] += av.y * bv.z; acc[1][3] += av.y * bv.w;
            acc[2][0] += av.z * bv.x; acc[2][1] += av.z * bv.y; acc[2][2] += av.z * bv.z; acc[2][3] += av.z * bv.w;
            acc[3][0] += av.w * bv.x; acc[3][1] += av.w * bv.y; acc[3][2] += av.w * bv.z; acc[3][3] += av.w * bv.w;
        }
        __syncthreads();
    }
    float* pp = part + (size_t)blockIdx.z * M * N;
#pragma unroll
    for (int i = 0; i < 4; ++i) {
        const int m = m0 + (ty << 2) + i;
#pragma unroll
        for (int j = 0; j < 4; ++j)
            pp[(size_t)m * N + n0 + (tx << 2) + j] = acc[i][j];
    }
}

// gather-A split-K: A row m = edge_rep[pair[2m + (kbeg>=512)]], col k (K=1024)
__global__ __launch_bounds__(256) void gemmsk_gather_kernel(
    const float* __restrict__ er, const int* __restrict__ pair,
    const float* __restrict__ B, float* __restrict__ part, int M, int N, int kchunk)
{
    __shared__ float As[16][68];
    __shared__ float Bs[16][68];
    const int m0 = blockIdx.x * 64, n0 = blockIdx.y * 64;
    const int kbeg = blockIdx.z * kchunk, kend = kbeg + kchunk;
    const int sel = (kbeg >= 512) ? 1 : 0;
    const int tid = threadIdx.x;
    const int ty = tid >> 4, tx = tid & 15;
    float acc[4][4] = {};
    for (int k0 = kbeg; k0 < kend; k0 += 16) {
        {
            const int m = tid >> 2, kq = (tid & 3) << 2;
            const int src = pair[2 * (m0 + m) + sel];
            const float4 a = *reinterpret_cast<const float4*>(er + (size_t)src * 1024 + k0 + kq);
            As[kq + 0][m] = a.x; As[kq + 1][m] = a.y; As[kq + 2][m] = a.z; As[kq + 3][m] = a.w;
        }
        {
            const int kk = tid >> 4, nq = (tid & 15) << 2;
            const float4 b = *reinterpret_cast<const float4*>(B + (size_t)(k0 + kk) * N + n0 + nq);
            *reinterpret_cast<float4*>(&Bs[kk][nq]) = b;
        }
        __syncthreads();
#pragma unroll
        for (int k = 0; k < 16; ++k) {
            const float4 av = *reinterpret_cast<const float4*>(&As[k][ty << 2]);
            const float4 bv = *reinterpret_cast<const float4*>(&Bs[k][tx << 2]);
            acc[0][0] += av.x * bv.x; acc[0][1] += av.x * bv.y; acc[0][2] += av.x * bv.z; acc[0][3] += av.x * bv.w;
            acc[1][0] += av.y * bv.x; acc[1][1] += av.y * bv.y; acc[1][2] += av.y * bv.z; acc[1][3] += av.y * bv.w;
            acc[2][0] += av.z * bv.x; acc[2][1] += av.z * bv.y; acc[2][2] += av.z * bv.z; acc[2][3] += av.z * bv.w;
            acc[3][0] += av.w * bv.x; acc[3][1] += av.w * bv.y; acc[3][2] += av.w * bv.z; acc[3][3] += av.w * bv.w;
        }
        __syncthreads();
    }
    float* pp = part + (size_t)blockIdx.z * M * N;
#pragma unroll
    for (int i = 0; i < 4; ++i) {
        const int m = m0 + (ty << 2) + i;
#pragma unroll
        for (int j = 0; j < 4; ++j)
            pp[(size_t)m * N + n0 + (tx << 2) + j] = acc[i][j];
    }
}

template<bool RELU, bool MUL>
__global__ __launch_bounds__(256) void reduce_kernel(
    const float* __restrict__ part, const float* __restrict__ bias,
    const float* __restrict__ mulp, float* __restrict__ C, int M, int N, int KS)
{
    const int idx = blockIdx.x * 256 + threadIdx.x;
    if (idx >= M * N) return;
    const int n = idx % N;
    float s = bias[n];
    for (int ks = 0; ks < KS; ++ks) s += part[(size_t)ks * M * N + idx];
    if (MUL) s *= mulp[idx];
    if (RELU) s = fmaxf(s, 0.f);
    C[idx] = s;
}

// ======================= conv1: separable 5x5 via rank-1 input ==============
__global__ __launch_bounds__(256) void conv1_kernel(
    const float* __restrict__ emb, const int* __restrict__ pair,
    const float* __restrict__ wgt, const float* __restrict__ bias,
    unsigned short* __restrict__ out, int n0, long out_stride)
{
    __shared__ float soe[200], sse[200];
    __shared__ float r[8][5][204];
    const int n = blockIdx.x, gn = n0 + n;
    const int co0 = blockIdx.y * 8;
    const int tid = threadIdx.x;
    const float* oe = emb + (size_t)(pair[2 * gn + 0] + 1) * 200;
    const float* se = emb + (size_t)(pair[2 * gn + 1] + 1) * 200;
    if (tid < 200) { soe[tid] = oe[tid]; sse[tid] = se[tid]; }
    __syncthreads();
    for (int it = tid; it < 8000; it += 256) {
        const int c = it / 1000;
        const int rem = it - c * 1000;
        const int dy = rem / 200;
        const int j = rem - dy * 200;
        const float* w = wgt + (size_t)(co0 + c) * 25 + dy * 5;
        float s = 0.f;
#pragma unroll
        for (int dx = 0; dx < 5; ++dx) {
            const int jj = j + dx - 2;
            if ((unsigned)jj < 200u) s += w[dx] * sse[jj];
        }
        r[c][dy][j] = s;
    }
    __syncthreads();
    float bz[8];
#pragma unroll
    for (int c = 0; c < 8; ++c) bz[c] = bias[co0 + c];
    for (int p = tid; p < 10000; p += 256) {
        const int py = p / 100, px = p - py * 100;
        const int i0 = 2 * py - 2, j0 = 2 * px;
        float ov[6];
#pragma unroll
        for (int t = 0; t < 6; ++t) {
            const int ii = i0 + t;
            ov[t] = ((unsigned)ii < 200u) ? soe[ii] : 0.f;
        }
        unsigned short vals[8];
#pragma unroll
        for (int c = 0; c < 8; ++c) {
            float s00 = bz[c], s01 = bz[c], s10 = bz[c], s11 = bz[c];
#pragma unroll
            for (int dy = 0; dy < 5; ++dy) {
                const float2 rv = *reinterpret_cast<const float2*>(&r[c][dy][j0]);
                s00 += ov[dy]     * rv.x; s01 += ov[dy]     * rv.y;
                s10 += ov[dy + 1] * rv.x; s11 += ov[dy + 1] * rv.y;
            }
            vals[c] = f2bf(0.25f * (fmaxf(s00, 0.f) + fmaxf(s01, 0.f) +
                                    fmaxf(s10, 0.f) + fmaxf(s11, 0.f)));
        }
        *reinterpret_cast<s16x8*>(out + (size_t)n * out_stride + (size_t)p * 64 + co0) =
            *reinterpret_cast<s16x8*>(vals);
    }
}

// ======= fused weight repack (all 3 convs): OIHW f32 -> A-fragment bf16 =====
__global__ __launch_bounds__(256) void frepack3_kernel(
    const float* __restrict__ w2, const float* __restrict__ w3, const float* __restrict__ w4,
    unsigned short* __restrict__ o2, unsigned short* __restrict__ o3, unsigned short* __restrict__ o4)
{
    const int b = blockIdx.x;
    const float* w; unsigned short* o; int CI, NSTEP, CLOG, base;
    if (b < 36)       { w = w2; o = o2; CI = 64;  NSTEP = 18; CLOG = 6; base = 0; }
    else if (b < 180) { w = w3; o = o3; CI = 128; NSTEP = 36; CLOG = 7; base = 36; }
    else              { w = w4; o = o4; CI = 256; NSTEP = 72; CLOG = 8; base = 180; }
    const int id = (b - base) * 256 + threadIdx.x;
    const int lane = id & 63;
    const int gt = id >> 6;
    const int t = gt % NSTEP, g = gt / NSTEP;
    const int co = g * 16 + (lane & 15);
    unsigned short r[8];
#pragma unroll
    for (int e = 0; e < 8; ++e) {
        const int kk = t * 32 + ((lane >> 4) << 3) + e;
        const int ci = kk & (CI - 1);
        const int dydx = kk >> CLOG;
        const int dy = dydx / 3, dx = dydx - dy * 3;
        r[e] = f2bf(w[((size_t)(co * CI + ci) * 3 + dy) * 3 + dx]);
    }
    *reinterpret_cast<s16x8*>(o + (size_t)id * 8) = *reinterpret_cast<s16x8*>(r);
}

// ======= LDS-staged implicit-GEMM MFMA 3x3 conv, pad=1, relu, NHWC bf16 =====
// R6 K-loop structure; b-address math reduced via the nf-stride identity
// (16 % NC == 0 for NC<=16 -> swizzle XOR term identical across nf) and a
// precomputed 9-bit validity mask per nf. conv4 (NC=32) keeps the old path.
// PIN fuses the 2x2 mean-pool into staging. blockIdx.x is XCD-swizzled.
template<int CI, int W, int CO_BLK, int PX_BLK, int WM, int WN, int MF, int NF, bool PIN>
__global__ __launch_bounds__(256) void convlds_kernel(
    const unsigned short* __restrict__ in, const unsigned short* __restrict__ wf,
    const float* __restrict__ bias, unsigned short* __restrict__ out,
    int CO, long in_stride, long out_stride)
{
    constexpr int NPIX = W * W;
    constexpr int K = 9 * CI;
    constexpr int NSTEP = K / 32;
    constexpr int NC = CI / 8;
    constexpr int NCL = (NC == 8) ? 3 : (NC == 16) ? 4 : 5;
    constexpr int CLOG = (CI == 64) ? 6 : (CI == 128) ? 7 : 8;
    constexpr int STAGE_PX = PX_BLK + 2 * W + 2;
    constexpr int TOT16 = STAGE_PX * NC;
    constexpr int WCO = CO_BLK / WM;
    constexpr int WPX = PX_BLK / WN;
    __shared__ unsigned short lds[(TOT16 + NC) * 8];

    const int tid = threadIdx.x;
    const unsigned short* inp = in + (size_t)blockIdx.z * in_stride;
    const int bx = xcd_swz(blockIdx.x, gridDim.x);
    const int p_base = bx * PX_BLK;
    const int q0 = p_base - (W + 1);

    // ---- stage input strip (clamped; borders handled by read predication) ----
    for (int i = tid; i < TOT16; i += 256) {
        const int s = i >> NCL;
        const int c = i & (NC - 1);
        int q = q0 + s;
        q = q < 0 ? 0 : (q >= NPIX ? NPIX - 1 : q);
        s16x8 v;
        if (PIN) {
            constexpr int WR = 2 * W;
            const int qy = q / W, qx = q - qy * W;
            const unsigned short* src = inp + ((size_t)(2 * qy) * WR + 2 * qx) * CI + c * 8;
            s16x8 va = *reinterpret_cast<const s16x8*>(src);
            s16x8 vb = *reinterpret_cast<const s16x8*>(src + CI);
            s16x8 vc = *reinterpret_cast<const s16x8*>(src + (size_t)WR * CI);
            s16x8 vd = *reinterpret_cast<const s16x8*>(src + (size_t)WR * CI + CI);
#pragma unroll
            for (int j = 0; j < 8; ++j)
                v[j] = (short)f2bf(0.25f * (bf2f((unsigned short)va[j]) + bf2f((unsigned short)vb[j]) +
                                            bf2f((unsigned short)vc[j]) + bf2f((unsigned short)vd[j])));
        } else {
            v = *reinterpret_cast<const s16x8*>(inp + (size_t)q * CI + c * 8);
        }
        const int perm = c ^ (s & (NC - 1));
        *reinterpret_cast<s16x8*>(&lds[(s * NC + perm) * 8]) = v;
    }
    if (tid < NC) *reinterpret_cast<s16x8*>(&lds[(TOT16 + tid) * 8]) = s16x8{};
    __syncthreads();

    const int lane = tid & 63, wid = tid >> 6;
    const int wm = wid % WM, wn = wid / WM;
    const int lhi = lane >> 4, llo = lane & 15;
    const int g0 = (blockIdx.y * CO_BLK + wm * WCO) >> 4;

    const unsigned short* pa[MF];
#pragma unroll
    for (int mf = 0; mf < MF; ++mf)
        pa[mf] = wf + ((size_t)(g0 + mf) * NSTEP * 64 + lane) * 8;

    int sb[NF], py[NF], px[NF];
    bool vp[NF];
    unsigned om[NF];
#pragma unroll
    for (int nf = 0; nf < NF; ++nf) {
        const int p = p_base + wn * WPX + nf * 16 + llo;
        vp[nf] = p < NPIX;
        py[nf] = p / W; px[nf] = p - py[nf] * W;
        sb[nf] = p - q0;
        unsigned m = 0;
#pragma unroll
        for (int d = 0; d < 9; ++d) {
            const int dy = d / 3, dx = d - (d / 3) * 3;
            const bool ok = vp[nf] && (unsigned)(py[nf] + dy - 1) < (unsigned)W
                                   && (unsigned)(px[nf] + dx - 1) < (unsigned)W;
            m |= (ok ? 1u : 0u) << d;
        }
        om[nf] = m;
    }

    f32x4 acc[MF][NF] = {};
#pragma unroll 2
    for (int t = 0; t < NSTEP; ++t) {
        const int k0 = t * 32;
        const int dydx = k0 >> CLOG;                // wave-uniform
        const int dy = dydx / 3, dx = dydx - dy * 3;
        const int delta = (dy - 1) * W + (dx - 1);
        const int cb = ((k0 & (CI - 1)) >> 3) + lhi;
        s16x8 a[MF], b[NF];
#pragma unroll
        for (int mf = 0; mf < MF; ++mf)
            a[mf] = *reinterpret_cast<const s16x8*>(pa[mf] + (size_t)t * 512);
        if (NC <= 16) {
            const int s0 = sb[0] + delta;
            const int ofs0 = s0 * NC + (cb ^ (s0 & (NC - 1)));
#pragma unroll
            for (int nf = 0; nf < NF; ++nf) {
                int ofs = ofs0 + nf * 16 * NC;
                ofs = ((om[nf] >> dydx) & 1u) ? ofs : TOT16;
                b[nf] = *reinterpret_cast<const s16x8*>(&lds[ofs * 8]);
            }
        } else {
#pragma unroll
            for (int nf = 0; nf < NF; ++nf) {
                const int s = sb[nf] + delta;
                const int iy = py[nf] + dy - 1, ix = px[nf] + dx - 1;
                const bool ok = vp[nf] && (unsigned)iy < (unsigned)W && (unsigned)ix < (unsigned)W;
                const int ofs = ok ? (s * NC + (cb ^ (s & (NC - 1)))) : TOT16;
                b[nf] = *reinterpret_cast<const s16x8*>(&lds[ofs * 8]);
            }
        }
#pragma unroll
        for (int mf = 0; mf < MF; ++mf)
#pragma unroll
            for (int nf = 0; nf < NF; ++nf)
                acc[mf][nf] = __builtin_amdgcn_mfma_f32_16x16x32_bf16(a[mf], b[nf], acc[mf][nf], 0, 0, 0);
    }

    unsigned short* outp = out + (size_t)blockIdx.z * out_stride;
#pragma unroll
    for (int mf = 0; mf < MF; ++mf) {
        const int co = blockIdx.y * CO_BLK + wm * WCO + mf * 16 + lhi * 4;
        const float b0 = bias[co], b1 = bias[co + 1], b2 = bias[co + 2], b3 = bias[co + 3];
#pragma unroll
        for (int nf = 0; nf < NF; ++nf) {
            if (!vp[nf]) continue;
            const int p = p_base + wn * WPX + nf * 16 + llo;
            f32x4 a = acc[mf][nf];
            unsigned short r[4];
            r[0] = f2bf(fmaxf(a.x + b0, 0.f));
            r[1] = f2bf(fmaxf(a.y + b1, 0.f));
            r[2] = f2bf(fmaxf(a.z + b2, 0.f));
            r[3] = f2bf(fmaxf(a.w + b3, 0.f));
            *reinterpret_cast<s16x4*>(outp + (size_t)p * CO + co) = *reinterpret_cast<s16x4*>(r);
        }
    }
}

// ======= global average pool over 625 pixels, NHWC bf16 -> f32 =======
__global__ __launch_bounds__(256) void gap_kernel(
    const unsigned short* __restrict__ in, float* __restrict__ gap,
    int n0, long in_stride)
{
    __shared__ float sm[4][512];
    const unsigned short* ip = in + (size_t)blockIdx.x * in_stride;
    const int g = threadIdx.x >> 6;
    const int c8 = threadIdx.x & 63;
    float s[8] = {};
    for (int p = g; p < 625; p += 4) {
        s16x8 v = *reinterpret_cast<const s16x8*>(ip + (size_t)p * 512 + c8 * 8);
#pragma unroll
        for (int j = 0; j < 8; ++j) s[j] += bf2f((unsigned short)v[j]);
    }
#pragma unroll
    for (int j = 0; j < 8; ++j) sm[g][c8 * 8 + j] = s[j];
    __syncthreads();
    if (g == 0) {
#pragma unroll
        for (int j = 0; j < 8; ++j) {
            const int ch = c8 * 8 + j;
            const float t = sm[0][ch] + sm[1][ch] + sm[2][ch] + sm[3][ch];
            gap[(size_t)(n0 + blockIdx.x) * 512 + ch] = t * (1.f / 625.f);
        }
    }
}

// ======= rcat reads edge_rep directly =======
__global__ __launch_bounds__(256) void rcat_kernel(
    const float* __restrict__ er, const int* __restrict__ pair,
    const float* __restrict__ ef, float* __restrict__ rc)
{
    const int r = blockIdx.x;
    const int p0 = pair[2 * r], p1 = pair[2 * r + 1];
    for (int i = threadIdx.x; i < 1536; i += 256) {
        float v;
        if (i < 512)       v = er[(size_t)p0 * 1024 + i];
        else if (i < 1024) v = ef[(size_t)r * 512 + (i - 512)];
        else               v = er[(size_t)p1 * 1024 + (i - 512)];
        rc[(size_t)r * 1536 + i] = v;
    }
}

__global__ __launch_bounds__(256) void reldist_kernel(
    const float* __restrict__ rf, const float* __restrict__ Wr, const float* __restrict__ br,
    const float* __restrict__ freq, const int* __restrict__ preds,
    const int* __restrict__ pair, float* __restrict__ out)
{
    const int idx = blockIdx.x * 256 + threadIdx.x;
    if (idx >= 128 * 51) return;
    const int r = idx / 51, j = idx - r * 51;
    const float* a = rf + (size_t)r * 512;
    float s = br[j];
    for (int k = 0; k < 512; ++k) s += a[k] * Wr[(size_t)k * 51 + j];
    const int c0 = preds[pair[2 * r]], c1 = preds[pair[2 * r + 1]];
    s += freq[((size_t)c0 * 151 + c1) * 51 + j];
    out[idx] = s;
}

// ===========================================================================
extern "C" void kernel_launch(void* const* d_in, const int* in_sizes, int n_in,
                              void* d_out, int out_size, void* d_ws, size_t ws_size,
                              hipStream_t stream)
{
    const float* obj_feats  = (const float*)d_in[0];
    const int*   obj_preds  = (const int*)  d_in[1];
    const int*   pair       = (const int*)  d_in[2];
    const float* unionf     = (const float*)d_in[3];
    const float* W_post_emb = (const float*)d_in[4];
    const float* b_post_emb = (const float*)d_in[5];
    const float* W_post_cat = (const float*)d_in[6];
    const float* b_post_cat = (const float*)d_in[7];
    const float* W_edge     = (const float*)d_in[8];
    const float* b_edge     = (const float*)d_in[9];
    const float* W_lin      = (const float*)d_in[10];
    const float* b_lin      = (const float*)d_in[11];
    const float* W_rel      = (const float*)d_in[12];
    const float* b_rel      = (const float*)d_in[13];
    const float* freq       = (const float*)d_in[14];
    const float* emb        = (const float*)d_in[15];
    const float* cw1 = (const float*)d_in[16]; const float* cb1 = (const float*)d_in[17];
    const float* cw2 = (const float*)d_in[18]; const float* cb2 = (const float*)d_in[19];
    const float* cw3 = (const float*)d_in[20]; const float* cb3 = (const float*)d_in[21];
    const float* cw4 = (const float*)d_in[22]; const float* cb4 = (const float*)d_in[23];
    const float* cw5 = (const float*)d_in[24]; const float* cb5 = (const float*)d_in[25];
    const float* cw6 = (const float*)d_in[26]; const float* cb6 = (const float*)d_in[27];
    const float* Ww1 = (const float*)d_in[28]; const float* bw1 = (const float*)d_in[29];
    const float* Ww2 = (const float*)d_in[30]; const float* bw2 = (const float*)d_in[31];
    float* out = (float*)d_out;

    // ---- workspace layout (floats) ----
    float* ws = (float*)d_ws;
    float* edge_rep   = ws;                       // 1024*1024
    float* visual     = edge_rep + 1048576;       // 128*4096
    float* edge_feats = visual + 524288;          // 128*512
    float* rcat       = edge_feats + 65536;       // 128*1536
    float* rel_feats  = rcat + 196608;            // 128*512
    float* gap        = rel_feats + 65536;        // 128*512
    float* x5         = gap + 65536;              // 128*384
    float* pwe        = x5 + 49152;               // 128*4096
    float* hbuf       = pwe + 524288;             // 128*512
    float* part       = hbuf + 65536;             // 2097152 (split-K partials)
    const size_t persist_f32 = 2555904ull + 2097152ull;

    unsigned short* wsu = (unsigned short*)(ws + persist_f32);
    unsigned short* w2r = wsu;                    // 128*576
    unsigned short* w3r = w2r + 73728;            // 256*1152
    unsigned short* w4r = w3r + 294912;           // 512*2304
    unsigned short* actA = w4r + 1179648;

    // chunk the conv pipeline through ws (3.84 MB/sample for actA+actB)
    int C = 128;
    const size_t base_bytes = persist_f32 * 4 + 1548288ull * 2;
    while (C > 1 && base_bytes + (size_t)C * 1920000ull * 2 > ws_size) C >>= 1;
    unsigned short* actB = actA + (size_t)C * 640000;

    // ---- relation branch ----
    gemm_kernel<false,false,false><<<dim3(16,16),256,0,stream>>>(obj_feats, W_post_emb, b_post_emb, nullptr, edge_rep, 1024,1024,512);
    gemmsk_gather_kernel<<<dim3(2,64,4),256,0,stream>>>(edge_rep, pair, W_post_cat, part, 128,4096, 256);
    reduce_kernel<false,true ><<<dim3(2048),256,0,stream>>>(part, b_post_cat, unionf, visual, 128,4096,4);
    gemmsk_kernel<false><<<dim3(2,8,16),256,0,stream>>>(visual, W_edge, part, 128,512,4096, 256);
    reduce_kernel<true ,false><<<dim3(256),256,0,stream>>>(part, b_edge, nullptr, edge_feats, 128,512,16);
    rcat_kernel<<<dim3(128),256,0,stream>>>(edge_rep, pair, edge_feats, rcat);
    gemmsk_kernel<false><<<dim3(2,8,8),256,0,stream>>>(rcat, W_lin, part, 128,512,1536, 192);
    reduce_kernel<false,false><<<dim3(256),256,0,stream>>>(part, b_lin, nullptr, rel_feats, 128,512,8);
    reldist_kernel<<<dim3(26),256,0,stream>>>(rel_feats, W_rel, b_rel, freq, obj_preds, pair, out);

    // ---- fused weight repack ----
    frepack3_kernel<<<dim3(756),256,0,stream>>>(cw2, cw3, cw4, w2r, w3r, w4r);

    // ---- conv chain (pools fused into conv3/conv4 staging; chunked) ----
    for (int n0 = 0; n0 < 128; n0 += C) {
        conv1_kernel<<<dim3(C,8),256,0,stream>>>(emb, pair, cw1, cb1, actA, n0, 640000);
        convlds_kernel<64,100,128,128,2,2,4,4,false><<<dim3(79,1,C),256,0,stream>>>(actA, w2r, cb2, actB, 128, 640000, 1280000);
        convlds_kernel<128,50,256,64,4,1,4,4,true ><<<dim3(40,1,C),256,0,stream>>>(actB, w3r, cb3, actA, 256, 1280000, 640000);
        convlds_kernel<256,25,512,32,4,1,8,2,true ><<<dim3(20,1,C),256,0,stream>>>(actA, w4r, cb4, actB, 512, 640000, 1280000);
        gap_kernel<<<dim3(C),256,0,stream>>>(actB, gap, n0, 1280000);
    }

    // ---- conv tail (1x1 convs as GEMMs, B^T layout) ----
    gemmsk_kernel<true ><<<dim3(2,6,8),256,0,stream>>>(gap, cw5, part, 128,384,512, 64);
    reduce_kernel<true ,false><<<dim3(192),256,0,stream>>>(part, cb5, nullptr, x5, 128,384,8);
    gemmsk_kernel<true ><<<dim3(2,64,4),256,0,stream>>>(x5, cw6, part, 128,4096,384, 96);
    reduce_kernel<false,false><<<dim3(2048),256,0,stream>>>(part, cb6, nullptr, pwe, 128,4096,4);

    // ---- union head (Ww1 split into two K=4096 GEMMs, no cat8) ----
    gemmsk_kernel<false><<<dim3(2,8,16),256,0,stream>>>(pwe, Ww1, part, 128,512,4096, 256);
    gemmsk_kernel<false><<<dim3(2,8,16),256,0,stream>>>(unionf, Ww1 + (size_t)4096 * 512, part + (size_t)16 * 65536, 128,512,4096, 256);
    reduce_kernel<true ,false><<<dim3(256),256,0,stream>>>(part, bw1, nullptr, hbuf, 128,512,32);
    gemmsk_kernel<false><<<dim3(2,64,4),256,0,stream>>>(hbuf, Ww2, part, 128,4096,512, 128);
    reduce_kernel<true ,false><<<dim3(2048),256,0,stream>>>(part, bw2, nullptr, out + 6528, 128,4096,4);
}

// Round 13
// 1273.755 us; speedup vs baseline: 1.0627x; 1.0627x over previous
//
#include <hip/hip_runtime.h>
#include <hip/hip_bf16.h>

// ---------------------------------------------------------------------------
// HID=512 POOL=4096 N_OBJ_CLS=151 N_REL_CLS=51 EMB=200 N_OBJ=1024 N_REL=128
// ---------------------------------------------------------------------------

typedef __attribute__((ext_vector_type(8))) short  s16x8;
typedef __attribute__((ext_vector_type(4))) short  s16x4;
typedef __attribute__((ext_vector_type(4))) float  f32x4;

__device__ inline unsigned short f2bf(float f) {
    unsigned u = __builtin_bit_cast(unsigned, f);
    u = (u + 0x7FFF + ((u >> 16) & 1)) >> 16;
    return (unsigned short)u;
}
__device__ inline float bf2f(unsigned short s) {
    unsigned u = ((unsigned)s) << 16;
    return __builtin_bit_cast(float, u);
}

// bijective chunked XCD swizzle (m204): neighbor strips land on same XCD L2
__device__ inline int xcd_swz(int o, int n) {
    const int q = n >> 3, r = n & 7;
    const int x = o & 7, j = o >> 3;
    const int base = (x < r) ? x * (q + 1) : r * (q + 1) + (x - r) * q;
    return base + j;
}

// ======================= generic f32 GEMM (64x64 tile) ======================
template<bool BT, bool RELU, bool MUL>
__global__ __launch_bounds__(256) void gemm_kernel(
    const float* __restrict__ A, const float* __restrict__ B,
    const float* __restrict__ bias, const float* __restrict__ mulp,
    float* __restrict__ C, int M, int N, int K)
{
    __shared__ float As[16][68];
    __shared__ float Bs[16][68];
    const int m0 = blockIdx.x * 64, n0 = blockIdx.y * 64;
    const int tid = threadIdx.x;
    const int ty = tid >> 4, tx = tid & 15;
    float acc[4][4] = {};
    for (int k0 = 0; k0 < K; k0 += 16) {
        {
            const int m = tid >> 2, kq = (tid & 3) << 2;
            const float4 a = *reinterpret_cast<const float4*>(A + (size_t)(m0 + m) * K + k0 + kq);
            As[kq + 0][m] = a.x; As[kq + 1][m] = a.y; As[kq + 2][m] = a.z; As[kq + 3][m] = a.w;
        }
        if (!BT) {
            const int kk = tid >> 4, nq = (tid & 15) << 2;
            const float4 b = *reinterpret_cast<const float4*>(B + (size_t)(k0 + kk) * N + n0 + nq);
            *reinterpret_cast<float4*>(&Bs[kk][nq]) = b;
        } else {
            const int nn = tid >> 2, kq = (tid & 3) << 2;
            const float4 b = *reinterpret_cast<const float4*>(B + (size_t)(n0 + nn) * K + k0 + kq);
            Bs[kq + 0][nn] = b.x; Bs[kq + 1][nn] = b.y; Bs[kq + 2][nn] = b.z; Bs[kq + 3][nn] = b.w;
        }
        __syncthreads();
#pragma unroll
        for (int k = 0; k < 16; ++k) {
            const float4 av = *reinterpret_cast<const float4*>(&As[k][ty << 2]);
            const float4 bv = *reinterpret_cast<const float4*>(&Bs[k][tx << 2]);
            acc[0][0] += av.x * bv.x; acc[0][1] += av.x * bv.y; acc[0][2] += av.x * bv.z; acc[0][3] += av.x * bv.w;
            acc[1][0] += av.y * bv.x; acc[1][1] += av.y * bv.y; acc[1][2] += av.y * bv.z; acc[1][3] += av.y * bv.w;
            acc[2][0] += av.z * bv.x; acc[2][1] += av.z * bv.y; acc[2][2] += av.z * bv.z; acc[2][3] += av.z * bv.w;
            acc[3][0] += av.w * bv.x; acc[3][1] += av.w * bv.y; acc[3][2] += av.w * bv.z; acc[3][3] += av.w * bv.w;
        }
        __syncthreads();
    }
#pragma unroll
    for (int i = 0; i < 4; ++i) {
        const int m = m0 + (ty << 2) + i;
#pragma unroll
        for (int j = 0; j < 4; ++j) {
            const int n = n0 + (tx << 2) + j;
            float v = acc[i][j] + bias[n];
            if (MUL) v *= mulp[(size_t)m * N + n];
            if (RELU) v = fmaxf(v, 0.f);
            C[(size_t)m * N + n] = v;
        }
    }
}

// =================== split-K f32 GEMM: partials + reduce ====================
template<bool BT>
__global__ __launch_bounds__(256) void gemmsk_kernel(
    const float* __restrict__ A, const float* __restrict__ B,
    float* __restrict__ part, int M, int N, int K, int kchunk)
{
    __shared__ float As[16][68];
    __shared__ float Bs[16][68];
    const int m0 = blockIdx.x * 64, n0 = blockIdx.y * 64;
    const int kbeg = blockIdx.z * kchunk, kend = kbeg + kchunk;
    const int tid = threadIdx.x;
    const int ty = tid >> 4, tx = tid & 15;
    float acc[4][4] = {};
    for (int k0 = kbeg; k0 < kend; k0 += 16) {
        {
            const int m = tid >> 2, kq = (tid & 3) << 2;
            const float4 a = *reinterpret_cast<const float4*>(A + (size_t)(m0 + m) * K + k0 + kq);
            As[kq + 0][m] = a.x; As[kq + 1][m] = a.y; As[kq + 2][m] = a.z; As[kq + 3][m] = a.w;
        }
        if (!BT) {
            const int kk = tid >> 4, nq = (tid & 15) << 2;
            const float4 b = *reinterpret_cast<const float4*>(B + (size_t)(k0 + kk) * N + n0 + nq);
            *reinterpret_cast<float4*>(&Bs[kk][nq]) = b;
        } else {
            const int nn = tid >> 2, kq = (tid & 3) << 2;
            const float4 b = *reinterpret_cast<const float4*>(B + (size_t)(n0 + nn) * K + k0 + kq);
            Bs[kq + 0][nn] = b.x; Bs[kq + 1][nn] = b.y; Bs[kq + 2][nn] = b.z; Bs[kq + 3][nn] = b.w;
        }
        __syncthreads();
#pragma unroll
        for (int k = 0; k < 16; ++k) {
            const float4 av = *reinterpret_cast<const float4*>(&As[k][ty << 2]);
            const float4 bv = *reinterpret_cast<const float4*>(&Bs[k][tx << 2]);
            acc[0][0] += av.x * bv.x; acc[0][1] += av.x * bv.y; acc[0][2] += av.x * bv.z; acc[0][3] += av.x * bv.w;
            acc[1][0] += av.y * bv.x; acc[1][1] += av.y * bv.y; acc[1][2] += av.y * bv.z; acc[1][3] += av.y * bv.w;
            acc[2][0] += av.z * bv.x; acc[2][1] += av.z * bv.y; acc[2][2] += av.z * bv.z; acc[2][3] += av.z * bv.w;
            acc[3][0] += av.w * bv.x; acc[3][1] += av.w * bv.y; acc[3][2] += av.w * bv.z; acc[3][3] += av.w * bv.w;
        }
        __syncthreads();
    }
    float* pp = part + (size_t)blockIdx.z * M * N;
#pragma unroll
    for (int i = 0; i < 4; ++i) {
        const int m = m0 + (ty << 2) + i;
#pragma unroll
        for (int j = 0; j < 4; ++j)
            pp[(size_t)m * N + n0 + (tx << 2) + j] = acc[i][j];
    }
}

// gather-A split-K: A row m = edge_rep[pair[2m + (kbeg>=512)]], col k (K=1024)
__global__ __launch_bounds__(256) void gemmsk_gather_kernel(
    const float* __restrict__ er, const int* __restrict__ pair,
    const float* __restrict__ B, float* __restrict__ part, int M, int N, int kchunk)
{
    __shared__ float As[16][68];
    __shared__ float Bs[16][68];
    const int m0 = blockIdx.x * 64, n0 = blockIdx.y * 64;
    const int kbeg = blockIdx.z * kchunk, kend = kbeg + kchunk;
    const int sel = (kbeg >= 512) ? 1 : 0;
    const int tid = threadIdx.x;
    const int ty = tid >> 4, tx = tid & 15;
    float acc[4][4] = {};
    for (int k0 = kbeg; k0 < kend; k0 += 16) {
        {
            const int m = tid >> 2, kq = (tid & 3) << 2;
            const int src = pair[2 * (m0 + m) + sel];
            const float4 a = *reinterpret_cast<const float4*>(er + (size_t)src * 1024 + k0 + kq);
            As[kq + 0][m] = a.x; As[kq + 1][m] = a.y; As[kq + 2][m] = a.z; As[kq + 3][m] = a.w;
        }
        {
            const int kk = tid >> 4, nq = (tid & 15) << 2;
            const float4 b = *reinterpret_cast<const float4*>(B + (size_t)(k0 + kk) * N + n0 + nq);
            *reinterpret_cast<float4*>(&Bs[kk][nq]) = b;
        }
        __syncthreads();
#pragma unroll
        for (int k = 0; k < 16; ++k) {
            const float4 av = *reinterpret_cast<const float4*>(&As[k][ty << 2]);
            const float4 bv = *reinterpret_cast<const float4*>(&Bs[k][tx << 2]);
            acc[0][0] += av.x * bv.x; acc[0][1] += av.x * bv.y; acc[0][2] += av.x * bv.z; acc[0][3] += av.x * bv.w;
            acc[1][0] += av.y * bv.x; acc[1][1] += av.y * bv.y; acc[1][2] += av.y * bv.z; acc[1][3] += av.y * bv.w;
            acc[2][0] += av.z * bv.x; acc[2][1] += av.z * bv.y; acc[2][2] += av.z * bv.z; acc[2][3] += av.z * bv.w;
            acc[3][0] += av.w * bv.x; acc[3][1] += av.w * bv.y; acc[3][2] += av.w * bv.z; acc[3][3] += av.w * bv.w;
        }
        __syncthreads();
    }
    float* pp = part + (size_t)blockIdx.z * M * N;
#pragma unroll
    for (int i = 0; i < 4; ++i) {
        const int m = m0 + (ty << 2) + i;
#pragma unroll
        for (int j = 0; j < 4; ++j)
            pp[(size_t)m * N + n0 + (tx << 2) + j] = acc[i][j];
    }
}

template<bool RELU, bool MUL>
__global__ __launch_bounds__(256) void reduce_kernel(
    const float* __restrict__ part, const float* __restrict__ bias,
    const float* __restrict__ mulp, float* __restrict__ C, int M, int N, int KS)
{
    const int idx = blockIdx.x * 256 + threadIdx.x;
    if (idx >= M * N) return;
    const int n = idx % N;
    float s = bias[n];
    for (int ks = 0; ks < KS; ++ks) s += part[(size_t)ks * M * N + idx];
    if (MUL) s *= mulp[idx];
    if (RELU) s = fmaxf(s, 0.f);
    C[idx] = s;
}

// ======================= conv1: separable 5x5 via rank-1 input ==============
__global__ __launch_bounds__(256) void conv1_kernel(
    const float* __restrict__ emb, const int* __restrict__ pair,
    const float* __restrict__ wgt, const float* __restrict__ bias,
    unsigned short* __restrict__ out, int n0, long out_stride)
{
    __shared__ float soe[200], sse[200];
    __shared__ float r[8][5][204];
    const int n = blockIdx.x, gn = n0 + n;
    const int co0 = blockIdx.y * 8;
    const int tid = threadIdx.x;
    const float* oe = emb + (size_t)(pair[2 * gn + 0] + 1) * 200;
    const float* se = emb + (size_t)(pair[2 * gn + 1] + 1) * 200;
    if (tid < 200) { soe[tid] = oe[tid]; sse[tid] = se[tid]; }
    __syncthreads();
    for (int it = tid; it < 8000; it += 256) {
        const int c = it / 1000;
        const int rem = it - c * 1000;
        const int dy = rem / 200;
        const int j = rem - dy * 200;
        const float* w = wgt + (size_t)(co0 + c) * 25 + dy * 5;
        float s = 0.f;
#pragma unroll
        for (int dx = 0; dx < 5; ++dx) {
            const int jj = j + dx - 2;
            if ((unsigned)jj < 200u) s += w[dx] * sse[jj];
        }
        r[c][dy][j] = s;
    }
    __syncthreads();
    float bz[8];
#pragma unroll
    for (int c = 0; c < 8; ++c) bz[c] = bias[co0 + c];
    for (int p = tid; p < 10000; p += 256) {
        const int py = p / 100, px = p - py * 100;
        const int i0 = 2 * py - 2, j0 = 2 * px;
        float ov[6];
#pragma unroll
        for (int t = 0; t < 6; ++t) {
            const int ii = i0 + t;
            ov[t] = ((unsigned)ii < 200u) ? soe[ii] : 0.f;
        }
        unsigned short vals[8];
#pragma unroll
        for (int c = 0; c < 8; ++c) {
            float s00 = bz[c], s01 = bz[c], s10 = bz[c], s11 = bz[c];
#pragma unroll
            for (int dy = 0; dy < 5; ++dy) {
                const float2 rv = *reinterpret_cast<const float2*>(&r[c][dy][j0]);
                s00 += ov[dy]     * rv.x; s01 += ov[dy]     * rv.y;
                s10 += ov[dy + 1] * rv.x; s11 += ov[dy + 1] * rv.y;
            }
            vals[c] = f2bf(0.25f * (fmaxf(s00, 0.f) + fmaxf(s01, 0.f) +
                                    fmaxf(s10, 0.f) + fmaxf(s11, 0.f)));
        }
        *reinterpret_cast<s16x8*>(out + (size_t)n * out_stride + (size_t)p * 64 + co0) =
            *reinterpret_cast<s16x8*>(vals);
    }
}

// ======= fused weight repack (all 3 convs): OIHW f32 -> A-fragment bf16 =====
__global__ __launch_bounds__(256) void frepack3_kernel(
    const float* __restrict__ w2, const float* __restrict__ w3, const float* __restrict__ w4,
    unsigned short* __restrict__ o2, unsigned short* __restrict__ o3, unsigned short* __restrict__ o4)
{
    const int b = blockIdx.x;
    const float* w; unsigned short* o; int CI, NSTEP, CLOG, base;
    if (b < 36)       { w = w2; o = o2; CI = 64;  NSTEP = 18; CLOG = 6; base = 0; }
    else if (b < 180) { w = w3; o = o3; CI = 128; NSTEP = 36; CLOG = 7; base = 36; }
    else              { w = w4; o = o4; CI = 256; NSTEP = 72; CLOG = 8; base = 180; }
    const int id = (b - base) * 256 + threadIdx.x;
    const int lane = id & 63;
    const int gt = id >> 6;
    const int t = gt % NSTEP, g = gt / NSTEP;
    const int co = g * 16 + (lane & 15);
    unsigned short r[8];
#pragma unroll
    for (int e = 0; e < 8; ++e) {
        const int kk = t * 32 + ((lane >> 4) << 3) + e;
        const int ci = kk & (CI - 1);
        const int dydx = kk >> CLOG;
        const int dy = dydx / 3, dx = dydx - dy * 3;
        r[e] = f2bf(w[((size_t)(co * CI + ci) * 3 + dy) * 3 + dx]);
    }
    *reinterpret_cast<s16x8*>(o + (size_t)id * 8) = *reinterpret_cast<s16x8*>(r);
}

// ======= LDS-staged implicit-GEMM MFMA 3x3 conv, pad=1, relu, NHWC bf16 =====
// R11-exact K-loop (proven fastest, 84 VGPR). ONLY change vs R11: blockIdx.x
// is XCD-swizzled so neighboring pixel strips (sharing halo) land on the same
// XCD L2 (R12 evidence: conv2 FETCH 213MB -> 46MB). PIN fuses the 2x2 pool.
template<int CI, int W, int CO_BLK, int PX_BLK, int WM, int WN, int MF, int NF, bool PIN>
__global__ __launch_bounds__(256) void convlds_kernel(
    const unsigned short* __restrict__ in, const unsigned short* __restrict__ wf,
    const float* __restrict__ bias, unsigned short* __restrict__ out,
    int CO, long in_stride, long out_stride)
{
    constexpr int NPIX = W * W;
    constexpr int K = 9 * CI;
    constexpr int NSTEP = K / 32;
    constexpr int NC = CI / 8;
    constexpr int NCL = (NC == 8) ? 3 : (NC == 16) ? 4 : 5;
    constexpr int CLOG = (CI == 64) ? 6 : (CI == 128) ? 7 : 8;
    constexpr int STAGE_PX = PX_BLK + 2 * W + 2;
    constexpr int TOT16 = STAGE_PX * NC;
    constexpr int WCO = CO_BLK / WM;
    constexpr int WPX = PX_BLK / WN;
    __shared__ unsigned short lds[(TOT16 + NC) * 8];

    const int tid = threadIdx.x;
    const unsigned short* inp = in + (size_t)blockIdx.z * in_stride;
    const int bx = xcd_swz(blockIdx.x, gridDim.x);
    const int p_base = bx * PX_BLK;
    const int q0 = p_base - (W + 1);

    // ---- stage input strip (clamped; borders handled by read predication) ----
    for (int i = tid; i < TOT16; i += 256) {
        const int s = i >> NCL;
        const int c = i & (NC - 1);
        int q = q0 + s;
        q = q < 0 ? 0 : (q >= NPIX ? NPIX - 1 : q);
        s16x8 v;
        if (PIN) {
            constexpr int WR = 2 * W;
            const int qy = q / W, qx = q - qy * W;
            const unsigned short* src = inp + ((size_t)(2 * qy) * WR + 2 * qx) * CI + c * 8;
            s16x8 va = *reinterpret_cast<const s16x8*>(src);
            s16x8 vb = *reinterpret_cast<const s16x8*>(src + CI);
            s16x8 vc = *reinterpret_cast<const s16x8*>(src + (size_t)WR * CI);
            s16x8 vd = *reinterpret_cast<const s16x8*>(src + (size_t)WR * CI + CI);
#pragma unroll
            for (int j = 0; j < 8; ++j)
                v[j] = (short)f2bf(0.25f * (bf2f((unsigned short)va[j]) + bf2f((unsigned short)vb[j]) +
                                            bf2f((unsigned short)vc[j]) + bf2f((unsigned short)vd[j])));
        } else {
            v = *reinterpret_cast<const s16x8*>(inp + (size_t)q * CI + c * 8);
        }
        const int perm = c ^ (s & (NC - 1));
        *reinterpret_cast<s16x8*>(&lds[(s * NC + perm) * 8]) = v;
    }
    if (tid < NC) *reinterpret_cast<s16x8*>(&lds[(TOT16 + tid) * 8]) = s16x8{};
    __syncthreads();

    const int lane = tid & 63, wid = tid >> 6;
    const int wm = wid % WM, wn = wid / WM;
    const int lhi = lane >> 4, llo = lane & 15;
    const int g0 = (blockIdx.y * CO_BLK + wm * WCO) >> 4;

    const unsigned short* pa[MF];
#pragma unroll
    for (int mf = 0; mf < MF; ++mf)
        pa[mf] = wf + ((size_t)(g0 + mf) * NSTEP * 64 + lane) * 8;

    int sb[NF], py[NF], px[NF];
    bool vp[NF];
#pragma unroll
    for (int nf = 0; nf < NF; ++nf) {
        const int p = p_base + wn * WPX + nf * 16 + llo;
        vp[nf] = p < NPIX;
        py[nf] = p / W; px[nf] = p - py[nf] * W;
        sb[nf] = p - q0;
    }

    f32x4 acc[MF][NF] = {};
#pragma unroll 2
    for (int t = 0; t < NSTEP; ++t) {
        const int k0 = t * 32;
        const int dydx = k0 >> CLOG;                // wave-uniform
        const int dy = dydx / 3, dx = dydx - dy * 3;
        const int delta = (dy - 1) * W + (dx - 1);
        const int cb = ((k0 & (CI - 1)) >> 3) + lhi;
        s16x8 a[MF], b[NF];
#pragma unroll
        for (int mf = 0; mf < MF; ++mf)
            a[mf] = *reinterpret_cast<const s16x8*>(pa[mf] + (size_t)t * 512);
#pragma unroll
        for (int nf = 0; nf < NF; ++nf) {
            const int s = sb[nf] + delta;
            const int iy = py[nf] + dy - 1, ix = px[nf] + dx - 1;
            const bool ok = vp[nf] && (unsigned)iy < (unsigned)W && (unsigned)ix < (unsigned)W;
            const int ofs = ok ? (s * NC + (cb ^ (s & (NC - 1)))) : TOT16;
            b[nf] = *reinterpret_cast<const s16x8*>(&lds[ofs * 8]);
        }
#pragma unroll
        for (int mf = 0; mf < MF; ++mf)
#pragma unroll
            for (int nf = 0; nf < NF; ++nf)
                acc[mf][nf] = __builtin_amdgcn_mfma_f32_16x16x32_bf16(a[mf], b[nf], acc[mf][nf], 0, 0, 0);
    }

    unsigned short* outp = out + (size_t)blockIdx.z * out_stride;
#pragma unroll
    for (int mf = 0; mf < MF; ++mf) {
        const int co = blockIdx.y * CO_BLK + wm * WCO + mf * 16 + lhi * 4;
        const float b0 = bias[co], b1 = bias[co + 1], b2 = bias[co + 2], b3 = bias[co + 3];
#pragma unroll
        for (int nf = 0; nf < NF; ++nf) {
            if (!vp[nf]) continue;
            const int p = p_base + wn * WPX + nf * 16 + llo;
            f32x4 a = acc[mf][nf];
            unsigned short r[4];
            r[0] = f2bf(fmaxf(a.x + b0, 0.f));
            r[1] = f2bf(fmaxf(a.y + b1, 0.f));
            r[2] = f2bf(fmaxf(a.z + b2, 0.f));
            r[3] = f2bf(fmaxf(a.w + b3, 0.f));
            *reinterpret_cast<s16x4*>(outp + (size_t)p * CO + co) = *reinterpret_cast<s16x4*>(r);
        }
    }
}

// ======= global average pool over 625 pixels, NHWC bf16 -> f32 =======
__global__ __launch_bounds__(256) void gap_kernel(
    const unsigned short* __restrict__ in, float* __restrict__ gap,
    int n0, long in_stride)
{
    __shared__ float sm[4][512];
    const unsigned short* ip = in + (size_t)blockIdx.x * in_stride;
    const int g = threadIdx.x >> 6;
    const int c8 = threadIdx.x & 63;
    float s[8] = {};
    for (int p = g; p < 625; p += 4) {
        s16x8 v = *reinterpret_cast<const s16x8*>(ip + (size_t)p * 512 + c8 * 8);
#pragma unroll
        for (int j = 0; j < 8; ++j) s[j] += bf2f((unsigned short)v[j]);
    }
#pragma unroll
    for (int j = 0; j < 8; ++j) sm[g][c8 * 8 + j] = s[j];
    __syncthreads();
    if (g == 0) {
#pragma unroll
        for (int j = 0; j < 8; ++j) {
            const int ch = c8 * 8 + j;
            const float t = sm[0][ch] + sm[1][ch] + sm[2][ch] + sm[3][ch];
            gap[(size_t)(n0 + blockIdx.x) * 512 + ch] = t * (1.f / 625.f);
        }
    }
}

// ======= rcat reads edge_rep directly =======
__global__ __launch_bounds__(256) void rcat_kernel(
    const float* __restrict__ er, const int* __restrict__ pair,
    const float* __restrict__ ef, float* __restrict__ rc)
{
    const int r = blockIdx.x;
    const int p0 = pair[2 * r], p1 = pair[2 * r + 1];
    for (int i = threadIdx.x; i < 1536; i += 256) {
        float v;
        if (i < 512)       v = er[(size_t)p0 * 1024 + i];
        else if (i < 1024) v = ef[(size_t)r * 512 + (i - 512)];
        else               v = er[(size_t)p1 * 1024 + (i - 512)];
        rc[(size_t)r * 1536 + i] = v;
    }
}

__global__ __launch_bounds__(256) void reldist_kernel(
    const float* __restrict__ rf, const float* __restrict__ Wr, const float* __restrict__ br,
    const float* __restrict__ freq, const int* __restrict__ preds,
    const int* __restrict__ pair, float* __restrict__ out)
{
    const int idx = blockIdx.x * 256 + threadIdx.x;
    if (idx >= 128 * 51) return;
    const int r = idx / 51, j = idx - r * 51;
    const float* a = rf + (size_t)r * 512;
    float s = br[j];
    for (int k = 0; k < 512; ++k) s += a[k] * Wr[(size_t)k * 51 + j];
    const int c0 = preds[pair[2 * r]], c1 = preds[pair[2 * r + 1]];
    s += freq[((size_t)c0 * 151 + c1) * 51 + j];
    out[idx] = s;
}

// ===========================================================================
extern "C" void kernel_launch(void* const* d_in, const int* in_sizes, int n_in,
                              void* d_out, int out_size, void* d_ws, size_t ws_size,
                              hipStream_t stream)
{
    const float* obj_feats  = (const float*)d_in[0];
    const int*   obj_preds  = (const int*)  d_in[1];
    const int*   pair       = (const int*)  d_in[2];
    const float* unionf     = (const float*)d_in[3];
    const float* W_post_emb = (const float*)d_in[4];
    const float* b_post_emb = (const float*)d_in[5];
    const float* W_post_cat = (const float*)d_in[6];
    const float* b_post_cat = (const float*)d_in[7];
    const float* W_edge     = (const float*)d_in[8];
    const float* b_edge     = (const float*)d_in[9];
    const float* W_lin      = (const float*)d_in[10];
    const float* b_lin      = (const float*)d_in[11];
    const float* W_rel      = (const float*)d_in[12];
    const float* b_rel      = (const float*)d_in[13];
    const float* freq       = (const float*)d_in[14];
    const float* emb        = (const float*)d_in[15];
    const float* cw1 = (const float*)d_in[16]; const float* cb1 = (const float*)d_in[17];
    const float* cw2 = (const float*)d_in[18]; const float* cb2 = (const float*)d_in[19];
    const float* cw3 = (const float*)d_in[20]; const float* cb3 = (const float*)d_in[21];
    const float* cw4 = (const float*)d_in[22]; const float* cb4 = (const float*)d_in[23];
    const float* cw5 = (const float*)d_in[24]; const float* cb5 = (const float*)d_in[25];
    const float* cw6 = (const float*)d_in[26]; const float* cb6 = (const float*)d_in[27];
    const float* Ww1 = (const float*)d_in[28]; const float* bw1 = (const float*)d_in[29];
    const float* Ww2 = (const float*)d_in[30]; const float* bw2 = (const float*)d_in[31];
    float* out = (float*)d_out;

    // ---- workspace layout (floats) ----
    float* ws = (float*)d_ws;
    float* edge_rep   = ws;                       // 1024*1024
    float* visual     = edge_rep + 1048576;       // 128*4096
    float* edge_feats = visual + 524288;          // 128*512
    float* rcat       = edge_feats + 65536;       // 128*1536
    float* rel_feats  = rcat + 196608;            // 128*512
    float* gap        = rel_feats + 65536;        // 128*512
    float* x5         = gap + 65536;              // 128*384
    float* pwe        = x5 + 49152;               // 128*4096
    float* hbuf       = pwe + 524288;             // 128*512
    float* part       = hbuf + 65536;             // 2097152 (split-K partials)
    const size_t persist_f32 = 2555904ull + 2097152ull;

    unsigned short* wsu = (unsigned short*)(ws + persist_f32);
    unsigned short* w2r = wsu;                    // 128*576
    unsigned short* w3r = w2r + 73728;            // 256*1152
    unsigned short* w4r = w3r + 294912;           // 512*2304
    unsigned short* actA = w4r + 1179648;

    // chunk the conv pipeline through ws (3.84 MB/sample for actA+actB)
    int C = 128;
    const size_t base_bytes = persist_f32 * 4 + 1548288ull * 2;
    while (C > 1 && base_bytes + (size_t)C * 1920000ull * 2 > ws_size) C >>= 1;
    unsigned short* actB = actA + (size_t)C * 640000;

    // ---- relation branch ----
    gemm_kernel<false,false,false><<<dim3(16,16),256,0,stream>>>(obj_feats, W_post_emb, b_post_emb, nullptr, edge_rep, 1024,1024,512);
    gemmsk_gather_kernel<<<dim3(2,64,4),256,0,stream>>>(edge_rep, pair, W_post_cat, part, 128,4096, 256);
    reduce_kernel<false,true ><<<dim3(2048),256,0,stream>>>(part, b_post_cat, unionf, visual, 128,4096,4);
    gemmsk_kernel<false><<<dim3(2,8,16),256,0,stream>>>(visual, W_edge, part, 128,512,4096, 256);
    reduce_kernel<true ,false><<<dim3(256),256,0,stream>>>(part, b_edge, nullptr, edge_feats, 128,512,16);
    rcat_kernel<<<dim3(128),256,0,stream>>>(edge_rep, pair, edge_feats, rcat);
    gemmsk_kernel<false><<<dim3(2,8,8),256,0,stream>>>(rcat, W_lin, part, 128,512,1536, 192);
    reduce_kernel<false,false><<<dim3(256),256,0,stream>>>(part, b_lin, nullptr, rel_feats, 128,512,8);
    reldist_kernel<<<dim3(26),256,0,stream>>>(rel_feats, W_rel, b_rel, freq, obj_preds, pair, out);

    // ---- fused weight repack ----
    frepack3_kernel<<<dim3(756),256,0,stream>>>(cw2, cw3, cw4, w2r, w3r, w4r);

    // ---- conv chain (pools fused into conv3/conv4 staging; chunked) ----
    for (int n0 = 0; n0 < 128; n0 += C) {
        conv1_kernel<<<dim3(C,8),256,0,stream>>>(emb, pair, cw1, cb1, actA, n0, 640000);
        convlds_kernel<64,100,128,128,2,2,4,4,false><<<dim3(79,1,C),256,0,stream>>>(actA, w2r, cb2, actB, 128, 640000, 1280000);
        convlds_kernel<128,50,256,64,4,1,4,4,true ><<<dim3(40,1,C),256,0,stream>>>(actB, w3r, cb3, actA, 256, 1280000, 640000);
        convlds_kernel<256,25,512,32,4,1,8,2,true ><<<dim3(20,1,C),256,0,stream>>>(actA, w4r, cb4, actB, 512, 640000, 1280000);
        gap_kernel<<<dim3(C),256,0,stream>>>(actB, gap, n0, 1280000);
    }

    // ---- conv tail (1x1 convs as GEMMs, B^T layout) ----
    gemmsk_kernel<true ><<<dim3(2,6,8),256,0,stream>>>(gap, cw5, part, 128,384,512, 64);
    reduce_kernel<true ,false><<<dim3(192),256,0,stream>>>(part, cb5, nullptr, x5, 128,384,8);
    gemmsk_kernel<true ><<<dim3(2,64,4),256,0,stream>>>(x5, cw6, part, 128,4096,384, 96);
    reduce_kernel<false,false><<<dim3(2048),256,0,stream>>>(part, cb6, nullptr, pwe, 128,4096,4);

    // ---- union head (Ww1 split into two K=4096 GEMMs, no cat8) ----
    gemmsk_kernel<false><<<dim3(2,8,16),256,0,stream>>>(pwe, Ww1, part, 128,512,4096, 256);
    gemmsk_kernel<false><<<dim3(2,8,16),256,0,stream>>>(unionf, Ww1 + (size_t)4096 * 512, part + (size_t)16 * 65536, 128,512,4096, 256);
    reduce_kernel<true ,false><<<dim3(256),256,0,stream>>>(part, bw1, nullptr, hbuf, 128,512,32);
    gemmsk_kernel<false><<<dim3(2,64,4),256,0,stream>>>(hbuf, Ww2, part, 128,4096,512, 128);
    reduce_kernel<true ,false><<<dim3(2048),256,0,stream>>>(part, bw2, nullptr, out + 6528, 128,4096,4);
}